// Round 5
// baseline (67.704 us; speedup 1.0000x reference)
//
#include <hip/hip_runtime.h>
#include <math.h>

// Problem constants
#define BATCH 32
#define SEQ   512
#define DIN   512
#define IFACE 919
#define TAILC 274     // iface columns 645..918 are the only ones used
#define TAIL0 645

// ws float offsets
#define XM_PART 0        // 32*16*512 = 262144 (partial seq sums, 16 chunks/batch)
#define EVO     262144   // 32*128 sigmoid(erase)
#define WVO     266240   // 32*128 write vector
#define WWH     270336   // 32*64  ww for n<64
#define SCAL    272384   // 32*2   [u, wwc]
#define RWV     272448   // 32*4   rw per head

// d_out float offsets (tuple concat: out, memory, link, usage, prec, ww, rw)
#define OUT_OFF   0
#define MEM_OFF   16384
#define LINK_OFF  4210688      // 32*1024*1024 floats of exact zeros
#define USAGE_OFF 37765120
#define PREC_OFF  37797888
#define WW_OFF    37830656
#define RW_OFF    37863424

typedef float f32x4 __attribute__((ext_vector_type(4)));

__device__ __forceinline__ float sigmoidf_(float x) { return 1.0f / (1.0f + expf(-x)); }

// K0: zero the link output (exactly 0) — 134 MB of nontemporal 16B stores.
// 8192 blocks x 256 threads x 4 exact grid-stride iterations.
__global__ void k_zero(f32x4* __restrict__ dst) {
    int idx = blockIdx.x * 256 + threadIdx.x;
    const int stride = 8192 * 256;
    f32x4 z = {0.f, 0.f, 0.f, 0.f};
    #pragma unroll
    for (int i = 0; i < 4; ++i)
        __builtin_nontemporal_store(z, &dst[idx + i * stride]);
}

// K1: partial reduce of x over seq. grid (16 chunks, 32 batch), 128 threads (float4/lane)
__global__ void k_reduce_x(const float* __restrict__ x, float* __restrict__ ws) {
    int c = blockIdx.x, b = blockIdx.y, t = threadIdx.x;
    const float4* xr = (const float4*)(x + (size_t)(b * SEQ + c * 32) * DIN);
    float4 acc = {0.f, 0.f, 0.f, 0.f};
    for (int s = 0; s < 32; ++s) {
        float4 v = xr[s * 128 + t];
        acc.x += v.x; acc.y += v.y; acc.z += v.z; acc.w += v.w;
    }
    ((float4*)(ws + XM_PART))[(b * 16 + c) * 128 + t] = acc;
}

// K2: one block per batch, 512 threads. Finish reduce -> GEMV (1 col/thread) -> params.
__global__ __launch_bounds__(512) void kB(float* __restrict__ ws,
                                          const float* __restrict__ Wif,
                                          float* __restrict__ out) {
    __shared__ float xms[DIN];
    __shared__ float p[TAILC];
    int b = blockIdx.x, t = threadIdx.x;

    {   // finish the two-stage reduce: sum 16 partials for dim t
        const float* q = ws + XM_PART + (size_t)b * 16 * DIN + t;
        float s = 0.f;
        #pragma unroll
        for (int c = 0; c < 16; ++c) s += q[c * DIN];
        xms[t] = s;
    }
    __syncthreads();

    if (t < TAILC) {   // GEMV: one column per thread
        const float* wcol = Wif + TAIL0 + t;
        float acc = 0.f;
        #pragma unroll 8
        for (int k = 0; k < DIN; ++k) acc += xms[k] * wcol[(size_t)k * IFACE];
        p[t] = acc * (1.0f / SEQ);
    }
    __syncthreads();

    // read_modes softmax, middle mode (redundant per thread, reads shared p)
    float rm1[4];
    #pragma unroll
    for (int r = 0; r < 4; ++r) {
        float i0 = p[262 + r], i1 = p[266 + r], i2 = p[270 + r];
        float mx = fmaxf(i0, fmaxf(i1, i2));
        float e0 = expf(i0 - mx), e1 = expf(i1 - mx), e2 = expf(i2 - mx);
        rm1[r] = e1 / (e0 + e1 + e2);
    }

    if (t < 128) {
        ws[EVO + b * 128 + t] = sigmoidf_(p[t]);          // sigmoid(erase)
        ws[WVO + b * 128 + t] = p[128 + t];               // write vector
        // out[b, w*4+r] = 1e-6 * read_modes[1][r]  (read_vectors collapse)
        float4 o = {1e-6f * rm1[0], 1e-6f * rm1[1], 1e-6f * rm1[2], 1e-6f * rm1[3]};
        ((float4*)(out + OUT_OFF))[b * 128 + t] = o;
    }

    if (t == 0) {
        const float inv1024 = 1.0f / 1024.0f;
        float ret = 1.f;
        #pragma unroll
        for (int r = 0; r < 4; ++r) {
            ws[RWV + b * 4 + r] = rm1[r] * inv1024;       // rw value per head
            float fg = sigmoidf_(p[256 + r]);
            ret *= (1.f - fg * rm1[r] * inv1024);
        }
        float u = 1e-6f * ret;                            // usage (constant over n)
        float ag = sigmoidf_(p[260]);
        float wg = sigmoidf_(p[261]);
        ws[SCAL + b * 2 + 0] = u;
        ws[SCAL + b * 2 + 1] = wg * (1.f - ag) * inv1024; // ww for n>=64 (alloc underflowed)
        float cum = 1.f;                                  // same f32 cumprod as reference
        for (int n = 0; n < 64; ++n) {
            float alloc = (1.f - u) * cum;
            ws[WWH + b * 64 + n] = wg * (ag * alloc + (1.f - ag) * inv1024);
            cum *= u;
        }
    }
}

// K3: blocks [0,4096): memory fill (16B NT store/thread); [4096,4224): small outputs.
__global__ void kC(const float* __restrict__ ws, float* __restrict__ out) {
    int bid = blockIdx.x;
    if (bid < 4096) {
        int idx = bid * 256 + threadIdx.x;   // < 1048576 float4
        int w4 = idx & 31;
        int n  = (idx >> 5) & 1023;
        int b  = idx >> 15;
        float ww = (n < 64) ? ws[WWH + b * 64 + n] : ws[SCAL + b * 2 + 1];
        float4 e = ((const float4*)(ws + EVO))[b * 32 + w4];
        float4 v = ((const float4*)(ws + WVO))[b * 32 + w4];
        f32x4 m;
        m.x = 1e-6f * (1.f - ww * e.x) + ww * v.x;
        m.y = 1e-6f * (1.f - ww * e.y) + ww * v.y;
        m.z = 1e-6f * (1.f - ww * e.z) + ww * v.z;
        m.w = 1e-6f * (1.f - ww * e.w) + ww * v.w;
        __builtin_nontemporal_store(m, &((f32x4*)(out + MEM_OFF))[idx]);
    } else {
        int t2 = (bid - 4096) * 256 + threadIdx.x;   // < 32768
        int b = t2 >> 10, n = t2 & 1023;
        float u  = ws[SCAL + b * 2 + 0];
        float ww = (n < 64) ? ws[WWH + b * 64 + n] : ws[SCAL + b * 2 + 1];
        out[USAGE_OFF + t2] = u;
        out[PREC_OFF + t2]  = ww;   // prec = ww (prec0 = 0)
        out[WW_OFF + t2]    = ww;
        float4 rv = ((const float4*)(ws + RWV))[b];
        ((float4*)out)[RW_OFF / 4 + t2] = rv;   // rw[b,n,:] constant over n
    }
}

extern "C" void kernel_launch(void* const* d_in, const int* in_sizes, int n_in,
                              void* d_out, int out_size, void* d_ws, size_t ws_size,
                              hipStream_t stream) {
    const float* x   = (const float*)d_in[0];
    const float* Wif = (const float*)d_in[1];
    float* out = (float*)d_out;
    float* ws  = (float*)d_ws;

    // link output is exactly zero (link0 = 0, prec0 = 0)
    k_zero<<<8192, 256, 0, stream>>>((f32x4*)(out + LINK_OFF));
    k_reduce_x<<<dim3(16, 32), 128, 0, stream>>>(x, ws);
    kB<<<32, 512, 0, stream>>>(ws, Wif, out);
    kC<<<4224, 256, 0, stream>>>(ws, out);
}

// Round 6
// 60.093 us; speedup vs baseline: 1.1267x; 1.1267x over previous
//
#include <hip/hip_runtime.h>
#include <math.h>

// Problem constants
#define BATCH 32
#define SEQ   512
#define DIN   512
#define IFACE 919
#define TAILC 274     // iface columns 645..918 are the only ones used
#define TAIL0 645

// ws float offsets
#define XM_PART 0        // 32*16*512 = 262144 (partial seq sums, 16 chunks/batch)
#define EVO     262144   // 32*128 sigmoid(erase)
#define WVO     266240   // 32*128 write vector
#define WWH     270336   // 32*64  ww for n<64
#define SCAL    272384   // 32*2   [u, wwc]
#define RWV     272448   // 32*4   rw per head

// d_out float offsets (tuple concat: out, memory, link, usage, prec, ww, rw)
#define OUT_OFF   0
#define MEM_OFF   16384
#define LINK_OFF  4210688      // 32*1024*1024 floats of exact zeros
#define USAGE_OFF 37765120
#define PREC_OFF  37797888
#define WW_OFF    37830656
#define RW_OFF    37863424

// kW block ranges (one 16B store per thread, fill-kernel shape)
#define ZB 32768               // link: 8388608 float4 / 256
#define MB 4096                // memory: 1048576 float4 / 256
#define SB 128                 // small: 32768 threads

__device__ __forceinline__ float sigmoidf_(float x) { return 1.0f / (1.0f + expf(-x)); }

// K1: partial reduce of x over seq. grid (16 chunks, 32 batch), 128 threads (float4/lane)
__global__ void k_reduce_x(const float* __restrict__ x, float* __restrict__ ws) {
    int c = blockIdx.x, b = blockIdx.y, t = threadIdx.x;
    const float4* xr = (const float4*)(x + (size_t)(b * SEQ + c * 32) * DIN);
    float4 acc = {0.f, 0.f, 0.f, 0.f};
    for (int s = 0; s < 32; ++s) {
        float4 v = xr[s * 128 + t];
        acc.x += v.x; acc.y += v.y; acc.z += v.z; acc.w += v.w;
    }
    ((float4*)(ws + XM_PART))[(b * 16 + c) * 128 + t] = acc;
}

// K2: one block per batch, 512 threads. Finish reduce -> GEMV (1 col/thread) -> params.
__global__ __launch_bounds__(512) void kB(float* __restrict__ ws,
                                          const float* __restrict__ Wif,
                                          float* __restrict__ out) {
    __shared__ float xms[DIN];
    __shared__ float p[TAILC];
    int b = blockIdx.x, t = threadIdx.x;

    {   // finish the two-stage reduce: sum 16 partials for dim t
        const float* q = ws + XM_PART + (size_t)b * 16 * DIN + t;
        float s = 0.f;
        #pragma unroll
        for (int c = 0; c < 16; ++c) s += q[c * DIN];
        xms[t] = s;
    }
    __syncthreads();

    if (t < TAILC) {   // GEMV: one column per thread
        const float* wcol = Wif + TAIL0 + t;
        float acc = 0.f;
        #pragma unroll 8
        for (int k = 0; k < DIN; ++k) acc += xms[k] * wcol[(size_t)k * IFACE];
        p[t] = acc * (1.0f / SEQ);
    }
    __syncthreads();

    // read_modes softmax, middle mode (redundant per thread, reads shared p)
    float rm1[4];
    #pragma unroll
    for (int r = 0; r < 4; ++r) {
        float i0 = p[262 + r], i1 = p[266 + r], i2 = p[270 + r];
        float mx = fmaxf(i0, fmaxf(i1, i2));
        float e0 = expf(i0 - mx), e1 = expf(i1 - mx), e2 = expf(i2 - mx);
        rm1[r] = e1 / (e0 + e1 + e2);
    }

    if (t < 128) {
        ws[EVO + b * 128 + t] = sigmoidf_(p[t]);          // sigmoid(erase)
        ws[WVO + b * 128 + t] = p[128 + t];               // write vector
        // out[b, w*4+r] = 1e-6 * read_modes[1][r]  (read_vectors collapse)
        float4 o = {1e-6f * rm1[0], 1e-6f * rm1[1], 1e-6f * rm1[2], 1e-6f * rm1[3]};
        ((float4*)(out + OUT_OFF))[b * 128 + t] = o;
    }

    if (t == 0) {
        const float inv1024 = 1.0f / 1024.0f;
        float ret = 1.f;
        #pragma unroll
        for (int r = 0; r < 4; ++r) {
            ws[RWV + b * 4 + r] = rm1[r] * inv1024;       // rw value per head
            float fg = sigmoidf_(p[256 + r]);
            ret *= (1.f - fg * rm1[r] * inv1024);
        }
        float u = 1e-6f * ret;                            // usage (constant over n)
        float ag = sigmoidf_(p[260]);
        float wg = sigmoidf_(p[261]);
        ws[SCAL + b * 2 + 0] = u;
        ws[SCAL + b * 2 + 1] = wg * (1.f - ag) * inv1024; // ww for n>=64 (alloc underflowed)
        float cum = 1.f;                                  // same f32 cumprod as reference
        for (int n = 0; n < 64; ++n) {
            float alloc = (1.f - u) * cum;
            ws[WWH + b * 64 + n] = wg * (ag * alloc + (1.f - ag) * inv1024);
            cum *= u;
        }
    }
}

// K3 (kW): all output writes, ONE plain 16B store per thread (fill-kernel shape).
// blocks [0,ZB): link zeros; [ZB, ZB+MB): memory fill; [ZB+MB, ZB+MB+SB): small.
__global__ void kW(const float* __restrict__ ws, float* __restrict__ out) {
    int bid = blockIdx.x;
    if (bid < ZB) {
        int idx = bid * 256 + threadIdx.x;      // < 8388608 float4
        float4 z = {0.f, 0.f, 0.f, 0.f};
        ((float4*)(out + LINK_OFF))[idx] = z;
    } else if (bid < ZB + MB) {
        int idx = (bid - ZB) * 256 + threadIdx.x;   // < 1048576 float4
        int w4 = idx & 31;
        int n  = (idx >> 5) & 1023;
        int b  = idx >> 15;
        float ww = (n < 64) ? ws[WWH + b * 64 + n] : ws[SCAL + b * 2 + 1];
        float4 e = ((const float4*)(ws + EVO))[b * 32 + w4];
        float4 v = ((const float4*)(ws + WVO))[b * 32 + w4];
        float4 m;
        m.x = 1e-6f * (1.f - ww * e.x) + ww * v.x;
        m.y = 1e-6f * (1.f - ww * e.y) + ww * v.y;
        m.z = 1e-6f * (1.f - ww * e.z) + ww * v.z;
        m.w = 1e-6f * (1.f - ww * e.w) + ww * v.w;
        ((float4*)(out + MEM_OFF))[idx] = m;
    } else {
        int t2 = (bid - ZB - MB) * 256 + threadIdx.x;   // < 32768
        int b = t2 >> 10, n = t2 & 1023;
        float u  = ws[SCAL + b * 2 + 0];
        float ww = (n < 64) ? ws[WWH + b * 64 + n] : ws[SCAL + b * 2 + 1];
        out[USAGE_OFF + t2] = u;
        out[PREC_OFF + t2]  = ww;   // prec = ww (prec0 = 0)
        out[WW_OFF + t2]    = ww;
        float4 rv = ((const float4*)(ws + RWV))[b];
        ((float4*)out)[RW_OFF / 4 + t2] = rv;   // rw[b,n,:] constant over n
    }
}

extern "C" void kernel_launch(void* const* d_in, const int* in_sizes, int n_in,
                              void* d_out, int out_size, void* d_ws, size_t ws_size,
                              hipStream_t stream) {
    const float* x   = (const float*)d_in[0];
    const float* Wif = (const float*)d_in[1];
    float* out = (float*)d_out;
    float* ws  = (float*)d_ws;

    k_reduce_x<<<dim3(16, 32), 128, 0, stream>>>(x, ws);
    kB<<<32, 512, 0, stream>>>(ws, Wif, out);
    kW<<<ZB + MB + SB, 256, 0, stream>>>(ws, out);
}